// Round 7
// baseline (173.819 us; speedup 1.0000x reference)
//
#include <hip/hip_runtime.h>
#include <hip/hip_fp16.h>
#include <math.h>

#define BATCH 4
#define SEQ   512
#define IND   256
#define NH    8
#define DKV   32
#define BH    32   // BATCH*NH
#define NTOK  2048 // BATCH*SEQ

typedef __attribute__((ext_vector_type(8))) short short8v;
typedef __attribute__((ext_vector_type(4))) float floatx4;

__device__ __forceinline__ unsigned f2bf1(float f) {
    unsigned u = __builtin_bit_cast(unsigned, f);
    return (u + 0x7fffu + ((u >> 16) & 1u)) >> 16;
}
__device__ __forceinline__ unsigned f2bf2(float lo, float hi) {
    return f2bf1(lo) | (f2bf1(hi) << 16);
}
__device__ __forceinline__ __half2 habs2_(__half2 x) {
    unsigned u = __builtin_bit_cast(unsigned, x) & 0x7fff7fffu;
    return __builtin_bit_cast(__half2, u);
}
__device__ __forceinline__ __half2 shfl_xor_h2(__half2 x, int m) {
    float f = __builtin_bit_cast(float, x);
    f = __shfl_xor(f, m, 64);
    return __builtin_bit_cast(__half2, f);
}

// ============ Kernel 1: fused LayerNorm + Q/K/V projections (bf16 MFMA) =====
// grid (32, 12): x = 64-row tile, y: which = y>>2 (0=q,1=k,2=v), n0 = (y&3)*64
// Q,K: f16 [bh][l][32].  V: bf16 TRANSPOSED [bh][d][512].
__global__ __launch_bounds__(256) void lnproj_kernel(
        const float* __restrict__ x,
        const float* __restrict__ gamma, const float* __restrict__ beta,
        const float* __restrict__ wq, const float* __restrict__ wk,
        const float* __restrict__ wv,
        float* __restrict__ xn, float* __restrict__ am,
        __half* __restrict__ Q, __half* __restrict__ K,
        unsigned short* __restrict__ Vt) {
    __shared__ __align__(16) unsigned short As[64][264];   // [m][k] bf16, full K
    __shared__ __align__(16) unsigned short Bs[2][64][40]; // [n][k] bf16, K-tile 32
    const int t = threadIdx.x;
    const int m0 = blockIdx.x * 64;
    const int y = blockIdx.y;
    const int which = y >> 2;
    const int n0 = (y & 3) * 64;
    const float* W = (which == 0) ? wq : (which == 1) ? wk : wv;

    // ---- Phase A: LayerNorm rows m0..m0+63 -> As (bf16) ----
    {
        const int r = t >> 2, q = t & 3;
        const float* xr = x + (m0 + r) * IND + q * 64;
        float4 xv[16];
        float s = 0.0f, s2 = 0.0f;
        #pragma unroll
        for (int i = 0; i < 16; i++) {
            xv[i] = *(const float4*)&xr[i * 4];
            s  += xv[i].x + xv[i].y + xv[i].z + xv[i].w;
            s2 += xv[i].x * xv[i].x + xv[i].y * xv[i].y
                + xv[i].z * xv[i].z + xv[i].w * xv[i].w;
        }
        s  += __shfl_xor(s, 1, 64);  s  += __shfl_xor(s, 2, 64);
        s2 += __shfl_xor(s2, 1, 64); s2 += __shfl_xor(s2, 2, 64);
        float mu = s * (1.0f / IND);
        float var = s2 * (1.0f / IND) - mu * mu;
        float rinv = rsqrtf(var + 1e-6f);
        const bool dox = (y == 0);
        if (dox && t < 64) am[m0 + t] = 0.0f;
        #pragma unroll
        for (int i = 0; i < 8; i++) {
            float4 a = xv[2 * i], bv = xv[2 * i + 1];
            float4 g0 = *(const float4*)&gamma[q * 64 + i * 8];
            float4 g1 = *(const float4*)&gamma[q * 64 + i * 8 + 4];
            float4 b0 = *(const float4*)&beta[q * 64 + i * 8];
            float4 b1 = *(const float4*)&beta[q * 64 + i * 8 + 4];
            float4 n0v, n1v;
            n0v.x = (a.x - mu) * rinv * g0.x + b0.x;
            n0v.y = (a.y - mu) * rinv * g0.y + b0.y;
            n0v.z = (a.z - mu) * rinv * g0.z + b0.z;
            n0v.w = (a.w - mu) * rinv * g0.w + b0.w;
            n1v.x = (bv.x - mu) * rinv * g1.x + b1.x;
            n1v.y = (bv.y - mu) * rinv * g1.y + b1.y;
            n1v.z = (bv.z - mu) * rinv * g1.z + b1.z;
            n1v.w = (bv.w - mu) * rinv * g1.w + b1.w;
            if (dox) {
                *(float4*)&xn[(m0 + r) * IND + q * 64 + i * 8] = n0v;
                *(float4*)&xn[(m0 + r) * IND + q * 64 + i * 8 + 4] = n1v;
            }
            uint4 pk;
            pk.x = f2bf2(n0v.x, n0v.y); pk.y = f2bf2(n0v.z, n0v.w);
            pk.z = f2bf2(n1v.x, n1v.y); pk.w = f2bf2(n1v.z, n1v.w);
            *(uint4*)&As[r][q * 64 + i * 8] = pk;
        }
    }

    // ---- Phase B: MFMA over K (B double-buffered per 32-k tile) ----
    const int w = t >> 6, l = t & 63;
    const int wm = (w >> 1) * 32, wn = (w & 1) * 32;
    const int fr = l & 15, fg = l >> 4;
    floatx4 acc[2][2];
    #pragma unroll
    for (int i = 0; i < 2; i++)
        #pragma unroll
        for (int j = 0; j < 2; j++) acc[i][j] = (floatx4)(0.0f);

    const int kl = t >> 4, nq = t & 15;
    auto stageB = [&](int kt, int buf) {
        float4 b0 = *(const float4*)&W[(kt * 32 + kl) * IND + n0 + nq * 4];
        float4 b1 = *(const float4*)&W[(kt * 32 + 16 + kl) * IND + n0 + nq * 4];
        Bs[buf][nq * 4 + 0][kl] = (unsigned short)f2bf1(b0.x);
        Bs[buf][nq * 4 + 1][kl] = (unsigned short)f2bf1(b0.y);
        Bs[buf][nq * 4 + 2][kl] = (unsigned short)f2bf1(b0.z);
        Bs[buf][nq * 4 + 3][kl] = (unsigned short)f2bf1(b0.w);
        Bs[buf][nq * 4 + 0][kl + 16] = (unsigned short)f2bf1(b1.x);
        Bs[buf][nq * 4 + 1][kl + 16] = (unsigned short)f2bf1(b1.y);
        Bs[buf][nq * 4 + 2][kl + 16] = (unsigned short)f2bf1(b1.z);
        Bs[buf][nq * 4 + 3][kl + 16] = (unsigned short)f2bf1(b1.w);
    };
    stageB(0, 0);
    __syncthreads();
    #pragma unroll
    for (int kt = 0; kt < 8; kt++) {
        if (kt < 7) stageB(kt + 1, (kt + 1) & 1);
        const int buf = kt & 1;
        short8v a0 = *(const short8v*)&As[wm + fr][kt * 32 + fg * 8];
        short8v a1 = *(const short8v*)&As[wm + 16 + fr][kt * 32 + fg * 8];
        short8v b0 = *(const short8v*)&Bs[buf][wn + fr][fg * 8];
        short8v b1 = *(const short8v*)&Bs[buf][wn + 16 + fr][fg * 8];
        acc[0][0] = __builtin_amdgcn_mfma_f32_16x16x32_bf16(a0, b0, acc[0][0], 0, 0, 0);
        acc[0][1] = __builtin_amdgcn_mfma_f32_16x16x32_bf16(a0, b1, acc[0][1], 0, 0, 0);
        acc[1][0] = __builtin_amdgcn_mfma_f32_16x16x32_bf16(a1, b0, acc[1][0], 0, 0, 0);
        acc[1][1] = __builtin_amdgcn_mfma_f32_16x16x32_bf16(a1, b1, acc[1][1], 0, 0, 0);
        __syncthreads();
    }

    // ---- Epilogue ----
    const float scale = (which == 0) ? 0.17677669529663687f : 1.0f;
    #pragma unroll
    for (int mi = 0; mi < 2; mi++)
        #pragma unroll
        for (int ni = 0; ni < 2; ni++)
            #pragma unroll
            for (int reg = 0; reg < 4; reg++) {
                int row = m0 + wm + mi * 16 + fg * 4 + reg;   // token
                int col = n0 + wn + ni * 16 + fr;             // 0..255
                int b = row >> 9, ll = row & 511;
                int h = col >> 5, d = col & 31;
                if (which == 2) {
                    Vt[(((b << 3) + h) * DKV + d) * SEQ + ll] =
                        (unsigned short)f2bf1(acc[mi][ni][reg]);
                } else {
                    __half* O = (which == 0) ? Q : K;
                    O[(((b << 3) + h) * SEQ + ll) * DKV + d] =
                        __float2half_rn(acc[mi][ni][reg] * scale);
                }
            }
}

// ============ Kernel 2: attention — LDS-staged Q, per-wave i-tile, MFMA PV ===
// grid (8, 32): block 256 = 4 waves; wave w owns i-tile i0 = bx*64 + w*16.
// Lane l: li = l&15 (i-row), jc = l>>4; lane's j's: jt*32 + jc*8 + c == A-frag.
// Q staged in LDS with XOR swizzle: logical 16B chunk cc of row j stored at
// physical chunk cc ^ ((j>>3)&3)  -> the 4 jc-groups read disjoint bank quads.
__global__ __launch_bounds__(256) void attn_kernel(
        const __half* __restrict__ Qh, const __half* __restrict__ Kh,
        const unsigned short* __restrict__ Vt,
        float* __restrict__ attn_out, float* __restrict__ am) {
    __shared__ __align__(16) __half Qs[SEQ * DKV];   // 32 KB
    const int t = threadIdx.x;
    const int w = t >> 6, l = t & 63;
    const int li = l & 15, jc = l >> 4;
    const int gy = blockIdx.y;
    const int i0 = blockIdx.x * 64 + w * 16;
    const int b = gy >> 3, h = gy & 7;
    const __half* Qb = Qh + gy * SEQ * DKV;
    const unsigned short* Vb = Vt + gy * DKV * SEQ;

    // ---- stage Q (swizzled) ----
    {
        const float4* Qg = (const float4*)Qb;
        float4* Qd = (float4*)Qs;
        #pragma unroll
        for (int n = 0; n < 8; n++) {
            int flat = n * 256 + t;            // 0..2047
            int row = flat >> 2, cc = flat & 3;
            int phys = cc ^ ((row >> 3) & 3);
            Qd[row * 4 + phys] = Qg[flat];
        }
    }

    // ---- K row (i0+li) in registers (global, overlaps staging) ----
    __half2 kreg[16];
    {
        const float4* kp = (const float4*)(Kh + (gy * SEQ + i0 + li) * DKV);
        #pragma unroll
        for (int c = 0; c < 4; c++) {
            float4 kv = kp[c];
            const __half2* k2 = (const __half2*)&kv;
            #pragma unroll
            for (int k = 0; k < 4; k++) kreg[c * 4 + k] = k2[k];
        }
    }
    __syncthreads();

    // ---- scores: 128 per lane from LDS Q ----
    __half2 sreg[64];
    float mx = -1e30f;
    #pragma unroll
    for (int jt = 0; jt < 16; jt++) {
        float sc[8];
        #pragma unroll
        for (int c = 0; c < 8; c++) {
            const int j = jt * 32 + jc * 8 + c;
            const float4* qp = (const float4*)(Qs + j * DKV);
            __half2 z = __float2half2_rn(0.0f);
            __half2 a0 = z, a1 = z;
            #pragma unroll
            for (int cc = 0; cc < 4; cc++) {
                float4 qv = qp[cc ^ jc];     // (j>>3)&3 == jc
                const __half2* q2 = (const __half2*)&qv;
                #pragma unroll
                for (int k = 0; k < 4; k++) {
                    __half2 d2 = habs2_(__hsub2(q2[k], kreg[cc * 4 + k]));
                    if (k & 1) a1 = __hadd2(a1, d2); else a0 = __hadd2(a0, d2);
                }
            }
            __half2 a = __hadd2(a0, a1);
            sc[c] = (__low2float(a) + __high2float(a)) * (1.0f / 32.0f);
            mx = fmaxf(mx, sc[c]);
        }
        #pragma unroll
        for (int q = 0; q < 4; q++)
            sreg[jt * 4 + q] = __halves2half2(__float2half_rn(sc[2 * q]),
                                              __float2half_rn(sc[2 * q + 1]));
    }
    // row max across the 4 jc-groups (wave-synchronous shuffles)
    mx = fmaxf(mx, __shfl_xor(mx, 16, 64));
    mx = fmaxf(mx, __shfl_xor(mx, 32, 64));

    // ---- exp + row sum ----
    float su = 0.0f;
    #pragma unroll
    for (int r = 0; r < 64; r++) {
        float lo = __expf(__low2float(sreg[r]) - mx);
        float hi = __expf(__high2float(sreg[r]) - mx);
        su += lo + hi;
        sreg[r] = __halves2half2(__float2half_rn(lo), __float2half_rn(hi));
    }
    su += __shfl_xor(su, 16, 64);
    su += __shfl_xor(su, 32, 64);
    const float inv = 1.0f / su;
    #pragma unroll
    for (int r = 0; r < 64; r++) {
        float lo = __low2float(sreg[r]) * inv;
        float hi = __high2float(sreg[r]) * inv;
        sreg[r] = __halves2half2(__float2half_rn(lo), __float2half_rn(hi));
    }

    // ---- PV via MFMA: full O[16 i][32 d] in this wave (all 512 j) ----
    floatx4 oacc[2];
    oacc[0] = (floatx4)(0.0f); oacc[1] = (floatx4)(0.0f);
    #pragma unroll
    for (int jt = 0; jt < 16; jt++) {
        uint4 pw;
        pw.x = f2bf2(__low2float(sreg[jt * 4 + 0]), __high2float(sreg[jt * 4 + 0]));
        pw.y = f2bf2(__low2float(sreg[jt * 4 + 1]), __high2float(sreg[jt * 4 + 1]));
        pw.z = f2bf2(__low2float(sreg[jt * 4 + 2]), __high2float(sreg[jt * 4 + 2]));
        pw.w = f2bf2(__low2float(sreg[jt * 4 + 3]), __high2float(sreg[jt * 4 + 3]));
        short8v pa = __builtin_bit_cast(short8v, pw);
        #pragma unroll
        for (int n = 0; n < 2; n++) {
            short8v bf = *(const short8v*)&Vb[(n * 16 + li) * SEQ + jt * 32 + jc * 8];
            oacc[n] = __builtin_amdgcn_mfma_f32_16x16x32_bf16(pa, bf, oacc[n], 0, 0, 0);
        }
    }
    // D layout: col = lane&15 = li (d-offset), row = (lane>>4)*4 + reg = i-row
    #pragma unroll
    for (int n = 0; n < 2; n++)
        #pragma unroll
        for (int r = 0; r < 4; r++)
            attn_out[(b * SEQ + i0 + jc * 4 + r) * IND + h * 32 + n * 16 + li] =
                oacc[n][r];

    // ---- am colsum over the wave's 16 i-rows (shfl butterfly over li) ----
    #pragma unroll
    for (int S = 1; S <= 8; S <<= 1)
        #pragma unroll
        for (int r = 0; r < 64; r++)
            sreg[r] = __hadd2(sreg[r], shfl_xor_h2(sreg[r], S));
    if (li == 0) {
        #pragma unroll
        for (int jt = 0; jt < 16; jt++)
            #pragma unroll
            for (int q = 0; q < 4; q++) {
                int jp = jt * 32 + jc * 8 + 2 * q;
                atomicAdd(&am[b * SEQ + jp],
                          __low2float(sreg[jt * 4 + q]) * 0.125f);
                atomicAdd(&am[b * SEQ + jp + 1],
                          __high2float(sreg[jt * 4 + q]) * 0.125f);
            }
    }
}

// ============ Kernel 3: FC(bf16 MFMA) + residual, + fused amnorm ============
// grid (33, 4): x<32 -> GEMM tile (m0=x*64, n0=y*64); x==32 -> amnorm batch y
__global__ __launch_bounds__(256) void fcam_kernel(
        const float* __restrict__ ao, const float* __restrict__ wfc,
        const float* __restrict__ xn, const float* __restrict__ am,
        float* __restrict__ out, float* __restrict__ out_am) {
    __shared__ __align__(16) unsigned short As[64][264];
    __shared__ __align__(16) unsigned short Bs[2][64][40];
    __shared__ float lmn[4], lmx[4];
    const int t = threadIdx.x;

    if (blockIdx.x == 32) {   // ---- amnorm for batch blockIdx.y ----
        int b = blockIdx.y;
        float v0 = am[b * SEQ + t];
        float v1 = am[b * SEQ + t + 256];
        float mn = fminf(v0, v1), mx = fmaxf(v0, v1);
        #pragma unroll
        for (int o = 32; o > 0; o >>= 1) {
            mn = fminf(mn, __shfl_xor(mn, o, 64));
            mx = fmaxf(mx, __shfl_xor(mx, o, 64));
        }
        int w = t >> 6;
        if ((t & 63) == 0) { lmn[w] = mn; lmx[w] = mx; }
        __syncthreads();
        mn = fminf(fminf(lmn[0], lmn[1]), fminf(lmn[2], lmn[3]));
        mx = fmaxf(fmaxf(lmx[0], lmx[1]), fmaxf(lmx[2], lmx[3]));
        float inv = 1.0f / (mx - mn);
        out_am[b * SEQ + t]       = (v0 - mn) * inv;
        out_am[b * SEQ + t + 256] = (v1 - mn) * inv;
        return;
    }

    const int m0 = blockIdx.x * 64;
    const int n0 = blockIdx.y * 64;

    {
        const int r = t >> 2, q = t & 3;
        const float* ar = ao + (m0 + r) * IND + q * 64;
        #pragma unroll
        for (int i = 0; i < 8; i++) {
            float4 a = *(const float4*)&ar[i * 8];
            float4 bv = *(const float4*)&ar[i * 8 + 4];
            uint4 pk;
            pk.x = f2bf2(a.x, a.y);  pk.y = f2bf2(a.z, a.w);
            pk.z = f2bf2(bv.x, bv.y); pk.w = f2bf2(bv.z, bv.w);
            *(uint4*)&As[r][q * 64 + i * 8] = pk;
        }
    }

    const int w = t >> 6, l = t & 63;
    const int wm = (w >> 1) * 32, wn = (w & 1) * 32;
    const int fr = l & 15, fg = l >> 4;
    floatx4 acc[2][2];
    #pragma unroll
    for (int i = 0; i < 2; i++)
        #pragma unroll
        for (int j = 0; j < 2; j++) acc[i][j] = (floatx4)(0.0f);

    const int kl = t >> 4, nq = t & 15;
    auto stageB = [&](int kt, int buf) {
        float4 b0 = *(const float4*)&wfc[(kt * 32 + kl) * IND + n0 + nq * 4];
        float4 b1 = *(const float4*)&wfc[(kt * 32 + 16 + kl) * IND + n0 + nq * 4];
        Bs[buf][nq * 4 + 0][kl] = (unsigned short)f2bf1(b0.x);
        Bs[buf][nq * 4 + 1][kl] = (unsigned short)f2bf1(b0.y);
        Bs[buf][nq * 4 + 2][kl] = (unsigned short)f2bf1(b0.z);
        Bs[buf][nq * 4 + 3][kl] = (unsigned short)f2bf1(b0.w);
        Bs[buf][nq * 4 + 0][kl + 16] = (unsigned short)f2bf1(b1.x);
        Bs[buf][nq * 4 + 1][kl + 16] = (unsigned short)f2bf1(b1.y);
        Bs[buf][nq * 4 + 2][kl + 16] = (unsigned short)f2bf1(b1.z);
        Bs[buf][nq * 4 + 3][kl + 16] = (unsigned short)f2bf1(b1.w);
    };
    stageB(0, 0);
    __syncthreads();
    #pragma unroll
    for (int kt = 0; kt < 8; kt++) {
        if (kt < 7) stageB(kt + 1, (kt + 1) & 1);
        const int buf = kt & 1;
        short8v a0 = *(const short8v*)&As[wm + fr][kt * 32 + fg * 8];
        short8v a1 = *(const short8v*)&As[wm + 16 + fr][kt * 32 + fg * 8];
        short8v b0 = *(const short8v*)&Bs[buf][wn + fr][fg * 8];
        short8v b1 = *(const short8v*)&Bs[buf][wn + 16 + fr][fg * 8];
        acc[0][0] = __builtin_amdgcn_mfma_f32_16x16x32_bf16(a0, b0, acc[0][0], 0, 0, 0);
        acc[0][1] = __builtin_amdgcn_mfma_f32_16x16x32_bf16(a0, b1, acc[0][1], 0, 0, 0);
        acc[1][0] = __builtin_amdgcn_mfma_f32_16x16x32_bf16(a1, b0, acc[1][0], 0, 0, 0);
        acc[1][1] = __builtin_amdgcn_mfma_f32_16x16x32_bf16(a1, b1, acc[1][1], 0, 0, 0);
        __syncthreads();
    }

    #pragma unroll
    for (int mi = 0; mi < 2; mi++)
        #pragma unroll
        for (int ni = 0; ni < 2; ni++)
            #pragma unroll
            for (int reg = 0; reg < 4; reg++) {
                int row = m0 + wm + mi * 16 + fg * 4 + reg;
                int col = n0 + wn + ni * 16 + fr;
                out[row * IND + col] = acc[mi][ni][reg] + xn[row * IND + col];
            }
}

extern "C" void kernel_launch(void* const* d_in, const int* in_sizes, int n_in,
                              void* d_out, int out_size, void* d_ws, size_t ws_size,
                              hipStream_t stream) {
    (void)in_sizes; (void)n_in; (void)out_size; (void)ws_size;
    const float* x     = (const float*)d_in[0];
    const float* w_q   = (const float*)d_in[1];
    const float* w_k   = (const float*)d_in[2];
    const float* w_v   = (const float*)d_in[3];
    const float* w_fc  = (const float*)d_in[4];
    const float* gamma = (const float*)d_in[5];
    const float* beta  = (const float*)d_in[6];
    float* out = (float*)d_out;

    float* ws = (float*)d_ws;
    float* xn = ws;                          // 2048*256 f32
    float* AO = xn + NTOK * IND;             // 2048*256 f32
    float* AM = AO + NTOK * IND;             // 2048 f32
    __half* Qh = (__half*)(AM + NTOK);       // 32*512*32 f16
    __half* Kh = Qh + BH * SEQ * DKV;        // 32*512*32 f16
    unsigned short* Vb16 = (unsigned short*)(Kh + BH * SEQ * DKV); // bf16 [bh][32][512]

    hipLaunchKernelGGL(lnproj_kernel, dim3(32, 12), dim3(256), 0, stream,
                       x, gamma, beta, w_q, w_k, w_v, xn, AM, Qh, Kh, Vb16);
    hipLaunchKernelGGL(attn_kernel, dim3(8, 32), dim3(256), 0, stream,
                       Qh, Kh, Vb16, AO, AM);
    hipLaunchKernelGGL(fcam_kernel, dim3(33, 4), dim3(256), 0, stream,
                       AO, w_fc, xn, AM, out, out + NTOK * IND);
}

// Round 8
// 68.389 us; speedup vs baseline: 2.5416x; 2.5416x over previous
//
#include <hip/hip_runtime.h>
#include <hip/hip_fp16.h>
#include <math.h>

#define BATCH 4
#define SEQ   512
#define IND   256
#define NH    8
#define DKV   32
#define BH    32   // BATCH*NH
#define NTOK  2048 // BATCH*SEQ

typedef __attribute__((ext_vector_type(8))) short short8v;
typedef __attribute__((ext_vector_type(4))) float floatx4;

__device__ __forceinline__ unsigned f2bf1(float f) {
    unsigned u = __builtin_bit_cast(unsigned, f);
    return (u + 0x7fffu + ((u >> 16) & 1u)) >> 16;
}
__device__ __forceinline__ unsigned f2bf2(float lo, float hi) {
    return f2bf1(lo) | (f2bf1(hi) << 16);
}
__device__ __forceinline__ __half2 habs2_(__half2 x) {
    unsigned u = __builtin_bit_cast(unsigned, x) & 0x7fff7fffu;
    return __builtin_bit_cast(__half2, u);
}

// ============ Kernel 1: fused LayerNorm + Q/K/V projections (bf16 MFMA) =====
// grid (32, 12): x = 64-row tile, y: which = y>>2 (0=q,1=k,2=v), n0 = (y&3)*64
// Q,K: f16 [bh][l][32].  V: bf16 TRANSPOSED [bh][d][512].
__global__ __launch_bounds__(256) void lnproj_kernel(
        const float* __restrict__ x,
        const float* __restrict__ gamma, const float* __restrict__ beta,
        const float* __restrict__ wq, const float* __restrict__ wk,
        const float* __restrict__ wv,
        float* __restrict__ xn, float* __restrict__ am,
        __half* __restrict__ Q, __half* __restrict__ K,
        unsigned short* __restrict__ Vt) {
    __shared__ __align__(16) unsigned short As[64][264];   // [m][k] bf16, full K
    __shared__ __align__(16) unsigned short Bs[2][64][40]; // [n][k] bf16, K-tile 32
    const int t = threadIdx.x;
    const int m0 = blockIdx.x * 64;
    const int y = blockIdx.y;
    const int which = y >> 2;
    const int n0 = (y & 3) * 64;
    const float* W = (which == 0) ? wq : (which == 1) ? wk : wv;

    // ---- Phase A: LayerNorm rows m0..m0+63 -> As (bf16) ----
    {
        const int r = t >> 2, q = t & 3;
        const float* xr = x + (m0 + r) * IND + q * 64;
        float4 xv[16];
        float s = 0.0f, s2 = 0.0f;
        #pragma unroll
        for (int i = 0; i < 16; i++) {
            xv[i] = *(const float4*)&xr[i * 4];
            s  += xv[i].x + xv[i].y + xv[i].z + xv[i].w;
            s2 += xv[i].x * xv[i].x + xv[i].y * xv[i].y
                + xv[i].z * xv[i].z + xv[i].w * xv[i].w;
        }
        s  += __shfl_xor(s, 1, 64);  s  += __shfl_xor(s, 2, 64);
        s2 += __shfl_xor(s2, 1, 64); s2 += __shfl_xor(s2, 2, 64);
        float mu = s * (1.0f / IND);
        float var = s2 * (1.0f / IND) - mu * mu;
        float rinv = rsqrtf(var + 1e-6f);
        const bool dox = (y == 0);
        if (dox && t < 64) am[m0 + t] = 0.0f;
        #pragma unroll
        for (int i = 0; i < 8; i++) {
            float4 a = xv[2 * i], bv = xv[2 * i + 1];
            float4 g0 = *(const float4*)&gamma[q * 64 + i * 8];
            float4 g1 = *(const float4*)&gamma[q * 64 + i * 8 + 4];
            float4 b0 = *(const float4*)&beta[q * 64 + i * 8];
            float4 b1 = *(const float4*)&beta[q * 64 + i * 8 + 4];
            float4 n0v, n1v;
            n0v.x = (a.x - mu) * rinv * g0.x + b0.x;
            n0v.y = (a.y - mu) * rinv * g0.y + b0.y;
            n0v.z = (a.z - mu) * rinv * g0.z + b0.z;
            n0v.w = (a.w - mu) * rinv * g0.w + b0.w;
            n1v.x = (bv.x - mu) * rinv * g1.x + b1.x;
            n1v.y = (bv.y - mu) * rinv * g1.y + b1.y;
            n1v.z = (bv.z - mu) * rinv * g1.z + b1.z;
            n1v.w = (bv.w - mu) * rinv * g1.w + b1.w;
            if (dox) {
                *(float4*)&xn[(m0 + r) * IND + q * 64 + i * 8] = n0v;
                *(float4*)&xn[(m0 + r) * IND + q * 64 + i * 8 + 4] = n1v;
            }
            uint4 pk;
            pk.x = f2bf2(n0v.x, n0v.y); pk.y = f2bf2(n0v.z, n0v.w);
            pk.z = f2bf2(n1v.x, n1v.y); pk.w = f2bf2(n1v.z, n1v.w);
            *(uint4*)&As[r][q * 64 + i * 8] = pk;
        }
    }

    // ---- Phase B: MFMA over K (B double-buffered per 32-k tile) ----
    const int w = t >> 6, l = t & 63;
    const int wm = (w >> 1) * 32, wn = (w & 1) * 32;
    const int fr = l & 15, fg = l >> 4;
    floatx4 acc[2][2];
    #pragma unroll
    for (int i = 0; i < 2; i++)
        #pragma unroll
        for (int j = 0; j < 2; j++) acc[i][j] = (floatx4)(0.0f);

    const int kl = t >> 4, nq = t & 15;
    auto stageB = [&](int kt, int buf) {
        float4 b0 = *(const float4*)&W[(kt * 32 + kl) * IND + n0 + nq * 4];
        float4 b1 = *(const float4*)&W[(kt * 32 + 16 + kl) * IND + n0 + nq * 4];
        Bs[buf][nq * 4 + 0][kl] = (unsigned short)f2bf1(b0.x);
        Bs[buf][nq * 4 + 1][kl] = (unsigned short)f2bf1(b0.y);
        Bs[buf][nq * 4 + 2][kl] = (unsigned short)f2bf1(b0.z);
        Bs[buf][nq * 4 + 3][kl] = (unsigned short)f2bf1(b0.w);
        Bs[buf][nq * 4 + 0][kl + 16] = (unsigned short)f2bf1(b1.x);
        Bs[buf][nq * 4 + 1][kl + 16] = (unsigned short)f2bf1(b1.y);
        Bs[buf][nq * 4 + 2][kl + 16] = (unsigned short)f2bf1(b1.z);
        Bs[buf][nq * 4 + 3][kl + 16] = (unsigned short)f2bf1(b1.w);
    };
    stageB(0, 0);
    __syncthreads();
    #pragma unroll
    for (int kt = 0; kt < 8; kt++) {
        if (kt < 7) stageB(kt + 1, (kt + 1) & 1);
        const int buf = kt & 1;
        short8v a0 = *(const short8v*)&As[wm + fr][kt * 32 + fg * 8];
        short8v a1 = *(const short8v*)&As[wm + 16 + fr][kt * 32 + fg * 8];
        short8v b0 = *(const short8v*)&Bs[buf][wn + fr][fg * 8];
        short8v b1 = *(const short8v*)&Bs[buf][wn + 16 + fr][fg * 8];
        acc[0][0] = __builtin_amdgcn_mfma_f32_16x16x32_bf16(a0, b0, acc[0][0], 0, 0, 0);
        acc[0][1] = __builtin_amdgcn_mfma_f32_16x16x32_bf16(a0, b1, acc[0][1], 0, 0, 0);
        acc[1][0] = __builtin_amdgcn_mfma_f32_16x16x32_bf16(a1, b0, acc[1][0], 0, 0, 0);
        acc[1][1] = __builtin_amdgcn_mfma_f32_16x16x32_bf16(a1, b1, acc[1][1], 0, 0, 0);
        __syncthreads();
    }

    // ---- Epilogue ----
    const float scale = (which == 0) ? 0.17677669529663687f : 1.0f;
    #pragma unroll
    for (int mi = 0; mi < 2; mi++)
        #pragma unroll
        for (int ni = 0; ni < 2; ni++)
            #pragma unroll
            for (int reg = 0; reg < 4; reg++) {
                int row = m0 + wm + mi * 16 + fg * 4 + reg;   // token
                int col = n0 + wn + ni * 16 + fr;             // 0..255
                int b = row >> 9, ll = row & 511;
                int h = col >> 5, d = col & 31;
                if (which == 2) {
                    Vt[(((b << 3) + h) * DKV + d) * SEQ + ll] =
                        (unsigned short)f2bf1(acc[mi][ni][reg]);
                } else {
                    __half* O = (which == 0) ? Q : K;
                    O[(((b << 3) + h) * SEQ + ll) * DKV + d] =
                        __float2half_rn(acc[mi][ni][reg] * scale);
                }
            }
}

// ============ Kernel 2: attention — round-4 score engine + MFMA PV ==========
// grid (32, 32): x = 16-row i-tile, y = bh; block 256 = 4 waves.
// Scores: thread (g=t>>5, jl=t&31) owns rows {i0+g, i0+g+8}, j = tile*128+m*32+jl.
// P staged to LDS bf16 [16][520]; PV: each wave redundantly computes full
// O[16][32] via 32 MFMAs (A-frag b128 from Pl, B-frag 16B global from Vt)
// and stores a disjoint 4-row quarter. One producer->consumer barrier only.
__global__ __launch_bounds__(256) void attn_kernel(
        const __half* __restrict__ Qh, const __half* __restrict__ Kh,
        const unsigned short* __restrict__ Vt,
        float* __restrict__ attn_out, float* __restrict__ am) {
    __shared__ __align__(16) __half Th[2][128][40];        // Q staging (20.5 KB)
    __shared__ __align__(16) unsigned short Pl[16][520];   // P bf16 (16.6 KB)
    const int t = threadIdx.x;
    const int w = t >> 6, l = t & 63;
    const int g = t >> 5, jl = t & 31;
    const int li = l & 15, jc = l >> 4;
    const int gy = blockIdx.y;
    const int i0 = blockIdx.x * 16;
    const int b = gy >> 3, h = gy & 7;
    const __half* Qb = Qh + gy * SEQ * DKV;
    const __half* Kb = Kh + gy * SEQ * DKV;
    const unsigned short* Vb = Vt + gy * DKV * SEQ;
    const int r0 = t >> 2, ch = t & 3;

    // K rows (i0+g, i0+g+8) in registers as half2
    __half2 ka[16], kb[16];
    {
        const float4* pa = (const float4*)(Kb + (i0 + g) * DKV);
        const float4* pb = (const float4*)(Kb + (i0 + g + 8) * DKV);
        #pragma unroll
        for (int c = 0; c < 4; c++) {
            float4 va = pa[c], vb = pb[c];
            const __half2* ha = (const __half2*)&va;
            const __half2* hb = (const __half2*)&vb;
            #pragma unroll
            for (int k = 0; k < 4; k++) { ka[c*4+k] = ha[k]; kb[c*4+k] = hb[k]; }
        }
    }

    float vals_a[16], vals_b[16];
    float4 pre0, pre1;

    // ---- Phase 1: scores (Q tiles of 128 rows, double-buffered) ----
    pre0 = *(const float4*)(Qb + r0 * DKV + ch * 8);
    pre1 = *(const float4*)(Qb + (r0 + 64) * DKV + ch * 8);
    *(float4*)&Th[0][r0][ch * 8] = pre0;
    *(float4*)&Th[0][r0 + 64][ch * 8] = pre1;
    __syncthreads();
    #pragma unroll
    for (int tile = 0; tile < 4; tile++) {
        const int buf = tile & 1;
        if (tile < 3) {
            pre0 = *(const float4*)(Qb + ((tile+1)*128 + r0) * DKV + ch * 8);
            pre1 = *(const float4*)(Qb + ((tile+1)*128 + r0 + 64) * DKV + ch * 8);
        }
        #pragma unroll
        for (int m = 0; m < 4; m++) {
            const int j = jl + m * 32;
            __half2 z = __float2half2_rn(0.0f);
            __half2 sa0 = z, sa1 = z, sb0 = z, sb1 = z;
            #pragma unroll
            for (int c = 0; c < 4; c++) {
                float4 qv = *(const float4*)&Th[buf][j][c * 8];
                const __half2* q2 = (const __half2*)&qv;
                #pragma unroll
                for (int k = 0; k < 4; k++) {
                    __half2 da = habs2_(__hsub2(q2[k], ka[c*4+k]));
                    __half2 db = habs2_(__hsub2(q2[k], kb[c*4+k]));
                    if (k & 1) { sa1 = __hadd2(sa1, da); sb1 = __hadd2(sb1, db); }
                    else       { sa0 = __hadd2(sa0, da); sb0 = __hadd2(sb0, db); }
                }
            }
            __half2 sa = __hadd2(sa0, sa1), sb = __hadd2(sb0, sb1);
            vals_a[tile*4+m] = (__low2float(sa) + __high2float(sa)) * (1.0f/32.0f);
            vals_b[tile*4+m] = (__low2float(sb) + __high2float(sb)) * (1.0f/32.0f);
        }
        if (tile < 3) {
            *(float4*)&Th[buf ^ 1][r0][ch * 8] = pre0;
            *(float4*)&Th[buf ^ 1][r0 + 64][ch * 8] = pre1;
        }
        __syncthreads();
    }

    // ---- Phase 2: softmax over j (32 jl lanes per row-group) ----
    float mxa = vals_a[0], mxb = vals_b[0];
    #pragma unroll
    for (int m = 1; m < 16; m++) {
        mxa = fmaxf(mxa, vals_a[m]); mxb = fmaxf(mxb, vals_b[m]);
    }
    #pragma unroll
    for (int s = 1; s <= 16; s <<= 1) {
        mxa = fmaxf(mxa, __shfl_xor(mxa, s, 64));
        mxb = fmaxf(mxb, __shfl_xor(mxb, s, 64));
    }
    float sua = 0.0f, sub = 0.0f;
    #pragma unroll
    for (int m = 0; m < 16; m++) {
        vals_a[m] = __expf(vals_a[m] - mxa); sua += vals_a[m];
        vals_b[m] = __expf(vals_b[m] - mxb); sub += vals_b[m];
    }
    #pragma unroll
    for (int s = 1; s <= 16; s <<= 1) {
        sua += __shfl_xor(sua, s, 64);
        sub += __shfl_xor(sub, s, 64);
    }
    float inva = 1.0f / sua, invb = 1.0f / sub;
    #pragma unroll
    for (int m = 0; m < 16; m++) { vals_a[m] *= inva; vals_b[m] *= invb; }

    // ---- Phase 3: write P to LDS (bf16), one barrier ----
    #pragma unroll
    for (int m = 0; m < 16; m++) {
        const int j = (m >> 2) * 128 + (m & 3) * 32 + jl;
        Pl[g][j]     = (unsigned short)f2bf1(vals_a[m]);
        Pl[g + 8][j] = (unsigned short)f2bf1(vals_b[m]);
    }
    __syncthreads();

    // ---- Phase 4: PV via MFMA — each wave computes full O, stores quarter ----
    floatx4 oacc[2];
    oacc[0] = (floatx4)(0.0f); oacc[1] = (floatx4)(0.0f);
    #pragma unroll
    for (int jt = 0; jt < 16; jt++) {
        short8v pa = *(const short8v*)&Pl[li][jt * 32 + jc * 8];
        #pragma unroll
        for (int n = 0; n < 2; n++) {
            short8v bf = *(const short8v*)&Vb[(n * 16 + li) * SEQ + jt * 32 + jc * 8];
            oacc[n] = __builtin_amdgcn_mfma_f32_16x16x32_bf16(pa, bf, oacc[n], 0, 0, 0);
        }
    }
    // D layout: col = l&15 = li (d), row = jc*4 + reg (i). Wave w stores jc==w.
    if (jc == w) {
        #pragma unroll
        for (int n = 0; n < 2; n++)
            #pragma unroll
            for (int r = 0; r < 4; r++)
                attn_out[(b * SEQ + i0 + jc * 4 + r) * IND + h * 32 + n * 16 + li] =
                    oacc[n][r];
    }

    // ---- Phase 5: am colsum from Pl (read-only) + atomics ----
    #pragma unroll
    for (int nn = 0; nn < 2; nn++) {
        const int j = t + nn * 256;
        float cs = 0.0f;
        #pragma unroll
        for (int i = 0; i < 16; i++)
            cs += __builtin_bit_cast(float, ((unsigned)Pl[i][j]) << 16);
        atomicAdd(&am[b * SEQ + j], cs * 0.125f);
    }
}

// ============ Kernel 3: FC(bf16 MFMA) + residual, + fused amnorm ============
// grid (33, 4): x<32 -> GEMM tile (m0=x*64, n0=y*64); x==32 -> amnorm batch y
__global__ __launch_bounds__(256) void fcam_kernel(
        const float* __restrict__ ao, const float* __restrict__ wfc,
        const float* __restrict__ xn, const float* __restrict__ am,
        float* __restrict__ out, float* __restrict__ out_am) {
    __shared__ __align__(16) unsigned short As[64][264];
    __shared__ __align__(16) unsigned short Bs[2][64][40];
    __shared__ float lmn[4], lmx[4];
    const int t = threadIdx.x;

    if (blockIdx.x == 32) {   // ---- amnorm for batch blockIdx.y ----
        int b = blockIdx.y;
        float v0 = am[b * SEQ + t];
        float v1 = am[b * SEQ + t + 256];
        float mn = fminf(v0, v1), mx = fmaxf(v0, v1);
        #pragma unroll
        for (int o = 32; o > 0; o >>= 1) {
            mn = fminf(mn, __shfl_xor(mn, o, 64));
            mx = fmaxf(mx, __shfl_xor(mx, o, 64));
        }
        int w = t >> 6;
        if ((t & 63) == 0) { lmn[w] = mn; lmx[w] = mx; }
        __syncthreads();
        mn = fminf(fminf(lmn[0], lmn[1]), fminf(lmn[2], lmn[3]));
        mx = fmaxf(fmaxf(lmx[0], lmx[1]), fmaxf(lmx[2], lmx[3]));
        float inv = 1.0f / (mx - mn);
        out_am[b * SEQ + t]       = (v0 - mn) * inv;
        out_am[b * SEQ + t + 256] = (v1 - mn) * inv;
        return;
    }

    const int m0 = blockIdx.x * 64;
    const int n0 = blockIdx.y * 64;

    {
        const int r = t >> 2, q = t & 3;
        const float* ar = ao + (m0 + r) * IND + q * 64;
        #pragma unroll
        for (int i = 0; i < 8; i++) {
            float4 a = *(const float4*)&ar[i * 8];
            float4 bv = *(const float4*)&ar[i * 8 + 4];
            uint4 pk;
            pk.x = f2bf2(a.x, a.y);  pk.y = f2bf2(a.z, a.w);
            pk.z = f2bf2(bv.x, bv.y); pk.w = f2bf2(bv.z, bv.w);
            *(uint4*)&As[r][q * 64 + i * 8] = pk;
        }
    }

    const int w = t >> 6, l = t & 63;
    const int wm = (w >> 1) * 32, wn = (w & 1) * 32;
    const int fr = l & 15, fg = l >> 4;
    floatx4 acc[2][2];
    #pragma unroll
    for (int i = 0; i < 2; i++)
        #pragma unroll
        for (int j = 0; j < 2; j++) acc[i][j] = (floatx4)(0.0f);

    const int kl = t >> 4, nq = t & 15;
    auto stageB = [&](int kt, int buf) {
        float4 b0 = *(const float4*)&wfc[(kt * 32 + kl) * IND + n0 + nq * 4];
        float4 b1 = *(const float4*)&wfc[(kt * 32 + 16 + kl) * IND + n0 + nq * 4];
        Bs[buf][nq * 4 + 0][kl] = (unsigned short)f2bf1(b0.x);
        Bs[buf][nq * 4 + 1][kl] = (unsigned short)f2bf1(b0.y);
        Bs[buf][nq * 4 + 2][kl] = (unsigned short)f2bf1(b0.z);
        Bs[buf][nq * 4 + 3][kl] = (unsigned short)f2bf1(b0.w);
        Bs[buf][nq * 4 + 0][kl + 16] = (unsigned short)f2bf1(b1.x);
        Bs[buf][nq * 4 + 1][kl + 16] = (unsigned short)f2bf1(b1.y);
        Bs[buf][nq * 4 + 2][kl + 16] = (unsigned short)f2bf1(b1.z);
        Bs[buf][nq * 4 + 3][kl + 16] = (unsigned short)f2bf1(b1.w);
    };
    stageB(0, 0);
    __syncthreads();
    #pragma unroll
    for (int kt = 0; kt < 8; kt++) {
        if (kt < 7) stageB(kt + 1, (kt + 1) & 1);
        const int buf = kt & 1;
        short8v a0 = *(const short8v*)&As[wm + fr][kt * 32 + fg * 8];
        short8v a1 = *(const short8v*)&As[wm + 16 + fr][kt * 32 + fg * 8];
        short8v b0 = *(const short8v*)&Bs[buf][wn + fr][fg * 8];
        short8v b1 = *(const short8v*)&Bs[buf][wn + 16 + fr][fg * 8];
        acc[0][0] = __builtin_amdgcn_mfma_f32_16x16x32_bf16(a0, b0, acc[0][0], 0, 0, 0);
        acc[0][1] = __builtin_amdgcn_mfma_f32_16x16x32_bf16(a0, b1, acc[0][1], 0, 0, 0);
        acc[1][0] = __builtin_amdgcn_mfma_f32_16x16x32_bf16(a1, b0, acc[1][0], 0, 0, 0);
        acc[1][1] = __builtin_amdgcn_mfma_f32_16x16x32_bf16(a1, b1, acc[1][1], 0, 0, 0);
        __syncthreads();
    }

    #pragma unroll
    for (int mi = 0; mi < 2; mi++)
        #pragma unroll
        for (int ni = 0; ni < 2; ni++)
            #pragma unroll
            for (int reg = 0; reg < 4; reg++) {
                int row = m0 + wm + mi * 16 + fg * 4 + reg;
                int col = n0 + wn + ni * 16 + fr;
                out[row * IND + col] = acc[mi][ni][reg] + xn[row * IND + col];
            }
}

extern "C" void kernel_launch(void* const* d_in, const int* in_sizes, int n_in,
                              void* d_out, int out_size, void* d_ws, size_t ws_size,
                              hipStream_t stream) {
    (void)in_sizes; (void)n_in; (void)out_size; (void)ws_size;
    const float* x     = (const float*)d_in[0];
    const float* w_q   = (const float*)d_in[1];
    const float* w_k   = (const float*)d_in[2];
    const float* w_v   = (const float*)d_in[3];
    const float* w_fc  = (const float*)d_in[4];
    const float* gamma = (const float*)d_in[5];
    const float* beta  = (const float*)d_in[6];
    float* out = (float*)d_out;

    float* ws = (float*)d_ws;
    float* xn = ws;                          // 2048*256 f32
    float* AO = xn + NTOK * IND;             // 2048*256 f32
    float* AM = AO + NTOK * IND;             // 2048 f32
    __half* Qh = (__half*)(AM + NTOK);       // 32*512*32 f16
    __half* Kh = Qh + BH * SEQ * DKV;        // 32*512*32 f16
    unsigned short* Vb16 = (unsigned short*)(Kh + BH * SEQ * DKV); // bf16 [bh][32][512]

    hipLaunchKernelGGL(lnproj_kernel, dim3(32, 12), dim3(256), 0, stream,
                       x, gamma, beta, w_q, w_k, w_v, xn, AM, Qh, Kh, Vb16);
    hipLaunchKernelGGL(attn_kernel, dim3(32, 32), dim3(256), 0, stream,
                       Qh, Kh, Vb16, AO, AM);
    hipLaunchKernelGGL(fcam_kernel, dim3(33, 4), dim3(256), 0, stream,
                       AO, w_fc, xn, AM, out, out + NTOK * IND);
}